// Round 1
// baseline (186.287 us; speedup 1.0000x reference)
//
#include <hip/hip_runtime.h>
#include <stdint.h>

// ---------------------------------------------------------------------------
// CritiGraph distance kernel: bit-exact reproduction of the JAX reference.
//
// Reference RNG tree (all from jax.random.key(42), threefry2x32):
//   kmask, kperm = split(key)
//   randint(kmask, (H,T,K,TP), 0, 2^16):  k1,k2 = split(kmask);
//       span=65536 divides 2^32 -> multiplier==0 -> value = lower_bits & 0xFFFF
//       where lower_bits = random_bits(k2, 64, shape)
//   perm: num_rounds = ceil(3*ln(513)/ln(2^32-1)) = 1 round:
//       _, subkey = split(kperm); sort_keys = random_bits(subkey, 32, (513,))
//       perm = stable-sort(arange(513)) by sort_keys
//
// JAX >= 0.5 defaults jax_threefry_partitionable=True:
//   split(key)[i]          = TF(key, (0, i))            (fold-like)
//   random_bits 64-bit[i]  = TF(k, (0,i)) -> (hi<<32)|lo
//   random_bits 32-bit[i]  = TF(k, (0,i)) -> hi ^ lo
// Legacy (partitionable=False) path kept under macro for fallback.
// ---------------------------------------------------------------------------

#define JAX_PARTITIONABLE 1

#define H_   16
#define TP_  16
#define K_   16
#define T_   2048
#define NC   513                       // 2*H*K + 1
#define MASK_SZ (H_ * T_ * K_ * TP_)   // 8388608

struct TFPair { uint32_t a, b; };

__host__ __device__ constexpr uint32_t rotl32(uint32_t x, int r) {
  return (x << r) | (x >> (32 - r));
}

__host__ __device__ constexpr TFPair tf2x32(uint32_t k0, uint32_t k1,
                                            uint32_t x0, uint32_t x1) {
  uint32_t ks0 = k0, ks1 = k1, ks2 = k0 ^ k1 ^ 0x1BD11BDAu;
  x0 += ks0; x1 += ks1;
  x0 += x1; x1 = rotl32(x1, 13); x1 ^= x0;
  x0 += x1; x1 = rotl32(x1, 15); x1 ^= x0;
  x0 += x1; x1 = rotl32(x1, 26); x1 ^= x0;
  x0 += x1; x1 = rotl32(x1,  6); x1 ^= x0;
  x0 += ks1; x1 += ks2 + 1u;
  x0 += x1; x1 = rotl32(x1, 17); x1 ^= x0;
  x0 += x1; x1 = rotl32(x1, 29); x1 ^= x0;
  x0 += x1; x1 = rotl32(x1, 16); x1 ^= x0;
  x0 += x1; x1 = rotl32(x1, 24); x1 ^= x0;
  x0 += ks2; x1 += ks0 + 2u;
  x0 += x1; x1 = rotl32(x1, 13); x1 ^= x0;
  x0 += x1; x1 = rotl32(x1, 15); x1 ^= x0;
  x0 += x1; x1 = rotl32(x1, 26); x1 ^= x0;
  x0 += x1; x1 = rotl32(x1,  6); x1 ^= x0;
  x0 += ks0; x1 += ks1 + 3u;
  x0 += x1; x1 = rotl32(x1, 17); x1 ^= x0;
  x0 += x1; x1 = rotl32(x1, 29); x1 ^= x0;
  x0 += x1; x1 = rotl32(x1, 16); x1 ^= x0;
  x0 += x1; x1 = rotl32(x1, 24); x1 ^= x0;
  x0 += ks1; x1 += ks2 + 4u;
  x0 += x1; x1 = rotl32(x1, 13); x1 ^= x0;
  x0 += x1; x1 = rotl32(x1, 15); x1 ^= x0;
  x0 += x1; x1 = rotl32(x1, 26); x1 ^= x0;
  x0 += x1; x1 = rotl32(x1,  6); x1 ^= x0;
  x0 += ks2; x1 += ks0 + 5u;
  return {x0, x1};
}

// ---- compile-time key derivation (jax.random.key(42) == (0,42)) -----------
#if JAX_PARTITIONABLE
// split(key): keys[i] = TF(key, (0, i))
constexpr TFPair KM = tf2x32(0u, 42u, 0u, 0u);   // kmask
constexpr TFPair KP = tf2x32(0u, 42u, 0u, 1u);   // kperm
// randint: k1,k2 = split(kmask); lower_bits uses k2 = TF(kmask,(0,1))
constexpr TFPair C2 = tf2x32(KM.a, KM.b, 0u, 1u);
constexpr uint32_t KLO0 = C2.a, KLO1 = C2.b;
// shuffle: _, subkey = split(kperm); subkey = TF(kperm,(0,1))
constexpr TFPair SB = tf2x32(KP.a, KP.b, 0u, 1u);
constexpr uint32_t KSUB0 = SB.a, KSUB1 = SB.b;
#else
// split(key): counts [0,1,2,3] -> pairs (0,2),(1,3); keys from halves
constexpr TFPair S0 = tf2x32(0u, 42u, 0u, 2u);
constexpr TFPair S1 = tf2x32(0u, 42u, 1u, 3u);
constexpr uint32_t KMASK0 = S0.a, KMASK1 = S1.a;   // kmask = (y0[0], y0[1])
constexpr uint32_t KPERM0 = S0.b, KPERM1 = S1.b;   // kperm = (y1[0], y1[1])
constexpr TFPair M0 = tf2x32(KMASK0, KMASK1, 0u, 2u);
constexpr TFPair M1 = tf2x32(KMASK0, KMASK1, 1u, 3u);
constexpr uint32_t KLO0 = M0.b, KLO1 = M1.b;       // k2 of split(kmask)
constexpr TFPair P0 = tf2x32(KPERM0, KPERM1, 0u, 2u);
constexpr TFPair P1 = tf2x32(KPERM0, KPERM1, 1u, 3u);
constexpr uint32_t KSUB0 = P0.b, KSUB1 = P1.b;     // subkey of split(kperm)
#endif

// ---- stage 1: build the 513-element permutation into d_ws -----------------
__global__ __launch_bounds__(256) void perm_kernel(int* __restrict__ perm) {
  __shared__ uint32_t keys[NC];
#if JAX_PARTITIONABLE
  // 32-bit random_bits, partitionable: bits[i] = hi^lo of TF(subkey,(0,i))
  for (int i = threadIdx.x; i < NC; i += blockDim.x) {
    TFPair r = tf2x32(KSUB0, KSUB1, 0u, (uint32_t)i);
    keys[i] = r.a ^ r.b;
  }
#else
  // legacy: counts iota(513) padded to 514, halves (i, 257+i) (last pair (256,0))
  for (int i = threadIdx.x; i < 257; i += blockDim.x) {
    uint32_t c1 = (i < 256) ? (uint32_t)(257 + i) : 0u;
    TFPair r = tf2x32(KSUB0, KSUB1, (uint32_t)i, c1);
    keys[i] = r.a;
    if (i < 256) keys[257 + i] = r.b;
  }
#endif
  __syncthreads();
  // stable ascending sort of vals=arange(NC) by keys: perm[rank[m]] = m
  for (int m = threadIdx.x; m < NC; m += blockDim.x) {
    uint32_t km = keys[m];
    int rank = 0;
    for (int j = 0; j < NC; ++j) {
      uint32_t kj = keys[j];
      rank += (int)((kj < km) | ((kj == km) & (j < m)));
    }
    perm[rank] = m;
  }
}

// ---- stage 2: one thread per output element (t, c, tp) --------------------
__global__ __launch_bounds__(256) void dist_kernel(
    const int* __restrict__ locations, const int* __restrict__ pos_idx,
    const float* __restrict__ norm, const int* __restrict__ perm,
    float* __restrict__ out) {
  int gid = blockIdx.x * 256 + threadIdx.x;
  if (gid >= T_ * NC * TP_) return;
  int tp   = gid & (TP_ - 1);
  int rest = gid >> 4;
  int c = rest % NC;
  int t = rest / NC;

  int m   = perm[c];
  int ori = locations[pos_idx[t] * TP_ + tp];

  int v;
  if (m == 256) {
    v = ori;
  } else {
    int j = (m < 256) ? m : (m - 257);
    int h = j >> 4;          // level
    int k = j & (K_ - 1);
    // flat index into (H, T, K, TP) mask tensor
    uint32_t idx = (uint32_t)(((h * T_ + t) * K_ + k) * TP_ + tp);
#if JAX_PARTITIONABLE
    TFPair r = tf2x32(KLO0, KLO1, 0u, idx);          // 64-bit word: (a<<32)|b
#else
    TFPair r = tf2x32(KLO0, KLO1, idx, (uint32_t)MASK_SZ + idx);
#endif
    uint32_t mask = r.b & ((1u << h) - 1u);          // randint %2^16 then &(2^h-1)
    v = (ori ^ (1 << h)) ^ (int)mask;
    if (m > 256) v = -v;
  }

  // _distance(v, ori, norm[t])
  float sg = ((v >= 0) == (ori >= 0)) ? 1.0f : -1.0f;
  uint32_t av = (uint32_t)(v   < 0 ? -v   : v);
  uint32_t ao = (uint32_t)(ori < 0 ? -ori : ori);
  uint32_t x  = (av ^ ao) + 1u;                      // <= 2^17, exact in f32
  int e = 32 - __clz((int)x);                        // bit length == frexp exp
  float s = (float)e * 0.0625f;                      // /16
  out[gid] = sg * (1.0f - s) * norm[t];
}

extern "C" void kernel_launch(void* const* d_in, const int* in_sizes, int n_in,
                              void* d_out, int out_size, void* d_ws, size_t ws_size,
                              hipStream_t stream) {
  const int*   locations = (const int*)d_in[0];
  const int*   pos_idx   = (const int*)d_in[1];
  const float* norm      = (const float*)d_in[2];
  float* out = (float*)d_out;
  int*   perm = (int*)d_ws;   // 513 ints

  hipLaunchKernelGGL(perm_kernel, dim3(1), dim3(256), 0, stream, perm);
  const int total = T_ * NC * TP_;
  hipLaunchKernelGGL(dist_kernel, dim3((total + 255) / 256), dim3(256), 0, stream,
                     locations, pos_idx, norm, perm, out);
}

// Round 2
// 145.704 us; speedup vs baseline: 1.2785x; 1.2785x over previous
//
#include <hip/hip_runtime.h>
#include <stdint.h>

// ---------------------------------------------------------------------------
// CritiGraph distance kernel: bit-exact reproduction of the JAX reference
// (jax_threefry_partitionable=True path, verified absmax 0.0 in round 1).
//
// Round-2 structure:
//   - perm_kernel: inv_perm[m] = stable-rank of sortkey[m] among 513 keys.
//   - dist_kernel: one thread per (j, t, tp), j in [0,256] block-uniform.
//       j < 256: one threefry -> mask -> v; write dist(v) to channel
//                inv_perm[j] and dist(-v) = (v==0 ? d : -d) to inv_perm[j+257].
//       j ==256: write 0.9375*norm (the ori channel) to inv_perm[256].
//     This halves the threefry count vs round 1 (8.39M vs 16.75M) and makes
//     h/k/mask-width/inv_perm all scalar (SGPR) per block.
// ---------------------------------------------------------------------------

#define H_   16
#define TP_  16
#define K_   16
#define T_   2048
#define NC   513                       // 2*H*K + 1

struct TFPair { uint32_t a, b; };

__host__ __device__ constexpr uint32_t rotl32(uint32_t x, int r) {
  return (x << r) | (x >> (32 - r));
}

__host__ __device__ constexpr TFPair tf2x32(uint32_t k0, uint32_t k1,
                                            uint32_t x0, uint32_t x1) {
  uint32_t ks0 = k0, ks1 = k1, ks2 = k0 ^ k1 ^ 0x1BD11BDAu;
  x0 += ks0; x1 += ks1;
  x0 += x1; x1 = rotl32(x1, 13); x1 ^= x0;
  x0 += x1; x1 = rotl32(x1, 15); x1 ^= x0;
  x0 += x1; x1 = rotl32(x1, 26); x1 ^= x0;
  x0 += x1; x1 = rotl32(x1,  6); x1 ^= x0;
  x0 += ks1; x1 += ks2 + 1u;
  x0 += x1; x1 = rotl32(x1, 17); x1 ^= x0;
  x0 += x1; x1 = rotl32(x1, 29); x1 ^= x0;
  x0 += x1; x1 = rotl32(x1, 16); x1 ^= x0;
  x0 += x1; x1 = rotl32(x1, 24); x1 ^= x0;
  x0 += ks2; x1 += ks0 + 2u;
  x0 += x1; x1 = rotl32(x1, 13); x1 ^= x0;
  x0 += x1; x1 = rotl32(x1, 15); x1 ^= x0;
  x0 += x1; x1 = rotl32(x1, 26); x1 ^= x0;
  x0 += x1; x1 = rotl32(x1,  6); x1 ^= x0;
  x0 += ks0; x1 += ks1 + 3u;
  x0 += x1; x1 = rotl32(x1, 17); x1 ^= x0;
  x0 += x1; x1 = rotl32(x1, 29); x1 ^= x0;
  x0 += x1; x1 = rotl32(x1, 16); x1 ^= x0;
  x0 += x1; x1 = rotl32(x1, 24); x1 ^= x0;
  x0 += ks1; x1 += ks2 + 4u;
  x0 += x1; x1 = rotl32(x1, 13); x1 ^= x0;
  x0 += x1; x1 = rotl32(x1, 15); x1 ^= x0;
  x0 += x1; x1 = rotl32(x1, 26); x1 ^= x0;
  x0 += x1; x1 = rotl32(x1,  6); x1 ^= x0;
  x0 += ks2; x1 += ks0 + 5u;
  return {x0, x1};
}

// ---- compile-time key derivation (jax.random.key(42) == (0,42)) -----------
// split(key): keys[i] = TF(key, (0, i))
constexpr TFPair KM = tf2x32(0u, 42u, 0u, 0u);   // kmask
constexpr TFPair KP = tf2x32(0u, 42u, 0u, 1u);   // kperm
// randint: k1,k2 = split(kmask); lower_bits uses k2 = TF(kmask,(0,1))
constexpr TFPair C2 = tf2x32(KM.a, KM.b, 0u, 1u);
constexpr uint32_t KLO0 = C2.a, KLO1 = C2.b;
// shuffle: _, subkey = split(kperm); subkey = TF(kperm,(0,1))
constexpr TFPair SB = tf2x32(KP.a, KP.b, 0u, 1u);
constexpr uint32_t KSUB0 = SB.a, KSUB1 = SB.b;

// ---- stage 1: inv_perm[m] = rank of sortkey[m] (stable) into d_ws ---------
__global__ __launch_bounds__(512) void perm_kernel(int* __restrict__ inv_perm) {
  __shared__ uint32_t keys[NC];
  for (int i = threadIdx.x; i < NC; i += 512) {
    TFPair r = tf2x32(KSUB0, KSUB1, 0u, (uint32_t)i);
    keys[i] = r.a ^ r.b;   // 32-bit random_bits, partitionable: hi^lo
  }
  __syncthreads();
  for (int m = threadIdx.x; m < NC; m += 512) {
    uint32_t km = keys[m];
    int rank = 0;
    for (int jj = 0; jj < NC; ++jj) {
      uint32_t kj = keys[jj];
      rank += (int)((kj < km) | ((kj == km) & (jj < m)));
    }
    inv_perm[m] = rank;    // output channel for source channel m
  }
}

// ---- stage 2: one thread per (j, t, tp); j block-uniform ------------------
// grid: 257 j-values x 128 blocks each; block = 256 threads = 16 t x 16 tp.
__global__ __launch_bounds__(256) void dist_kernel(
    const int* __restrict__ locations, const int* __restrict__ pos_idx,
    const float* __restrict__ norm, const int* __restrict__ inv_perm,
    float* __restrict__ out) {
  const int j      = blockIdx.x >> 7;                          // 0..256, SGPR
  const int within = ((blockIdx.x & 127) << 8) | threadIdx.x;  // 0..32767
  const int t  = within >> 4;
  const int tp = within & 15;

  const int   ori = locations[pos_idx[t] * TP_ + tp];
  const float nm  = norm[t];
  const int   base = t * NC * TP_ + tp;

  if (j == 256) {                      // the 'ori' channel: dist(ori,ori)
    out[base + inv_perm[256] * TP_] = 0.9375f * nm;
    return;
  }

  const int h = j >> 4, k = j & (K_ - 1);      // SGPR
  // flat index into (H, T, K, TP) mask tensor
  const uint32_t idx = (uint32_t)(((h * T_ + t) * K_ + k) * TP_ + tp);
  const TFPair r = tf2x32(KLO0, KLO1, 0u, idx);     // 64-bit word (a<<32)|b
  const uint32_t mask = r.b & ((1u << h) - 1u);     // %2^16 then &(2^h-1)
  const int v = (ori ^ (1 << h)) ^ (int)mask;

  // dist(v, ori): sign product * (1 - bitlen(|v|^|ori| + 1)/16) * norm
  const float sg = ((v >= 0) == (ori >= 0)) ? 1.0f : -1.0f;
  const uint32_t av = (uint32_t)(v   < 0 ? -v   : v);
  const uint32_t ao = (uint32_t)(ori < 0 ? -ori : ori);
  const uint32_t x  = (av ^ ao) + 1u;               // <= 2^17, exact in f32
  const int e = 32 - __clz((int)x);                 // bit length == frexp exp
  const float d1 = sg * (1.0f - (float)e * 0.0625f) * nm;
  // dist(-v, ori): |−v|==|v|, sign flips unless v==0
  const float d2 = (v == 0) ? d1 : -d1;

  out[base + inv_perm[j]       * TP_] = d1;
  out[base + inv_perm[j + 257] * TP_] = d2;
}

extern "C" void kernel_launch(void* const* d_in, const int* in_sizes, int n_in,
                              void* d_out, int out_size, void* d_ws, size_t ws_size,
                              hipStream_t stream) {
  const int*   locations = (const int*)d_in[0];
  const int*   pos_idx   = (const int*)d_in[1];
  const float* norm      = (const float*)d_in[2];
  float* out      = (float*)d_out;
  int*   inv_perm = (int*)d_ws;   // 513 ints

  hipLaunchKernelGGL(perm_kernel, dim3(1), dim3(512), 0, stream, inv_perm);
  hipLaunchKernelGGL(dist_kernel, dim3(257 * 128), dim3(256), 0, stream,
                     locations, pos_idx, norm, inv_perm, out);
}

// Round 3
// 116.554 us; speedup vs baseline: 1.5983x; 1.2501x over previous
//
#include <hip/hip_runtime.h>
#include <stdint.h>

// ---------------------------------------------------------------------------
// CritiGraph distance kernel: bit-exact reproduction of the JAX reference
// (jax_threefry_partitionable=True path, verified absmax 0.0 rounds 1-2).
//
// Round-3 structure:
//   - The 513-channel permutation depends only on key(42) -> computed at
//     COMPILE TIME (constexpr threefry + chunked constexpr stable-rank,
//     16 parts to stay under clang's constexpr step budget) and embedded
//     in __constant__ memory. perm_kernel and its launch are gone.
//   - dist_kernel: block-uniform j-group of 4; each thread handles one
//     (t,tp) and 4 j-values: 4 independent threefry chains (ILP), one
//     ori/norm gather amortized over 8 output stores. Sign handling via
//     sign-bit XOR (sg=+-1 exactly). j==256 channel folded into jg==0.
// ---------------------------------------------------------------------------

#define H_   16
#define TP_  16
#define K_   16
#define T_   2048
#define NC   513                       // 2*H*K + 1

struct TFPair { uint32_t a, b; };

__host__ __device__ constexpr uint32_t rotl32(uint32_t x, int r) {
  return (x << r) | (x >> (32 - r));
}

__host__ __device__ constexpr TFPair tf2x32(uint32_t k0, uint32_t k1,
                                            uint32_t x0, uint32_t x1) {
  uint32_t ks0 = k0, ks1 = k1, ks2 = k0 ^ k1 ^ 0x1BD11BDAu;
  x0 += ks0; x1 += ks1;
  x0 += x1; x1 = rotl32(x1, 13); x1 ^= x0;
  x0 += x1; x1 = rotl32(x1, 15); x1 ^= x0;
  x0 += x1; x1 = rotl32(x1, 26); x1 ^= x0;
  x0 += x1; x1 = rotl32(x1,  6); x1 ^= x0;
  x0 += ks1; x1 += ks2 + 1u;
  x0 += x1; x1 = rotl32(x1, 17); x1 ^= x0;
  x0 += x1; x1 = rotl32(x1, 29); x1 ^= x0;
  x0 += x1; x1 = rotl32(x1, 16); x1 ^= x0;
  x0 += x1; x1 = rotl32(x1, 24); x1 ^= x0;
  x0 += ks2; x1 += ks0 + 2u;
  x0 += x1; x1 = rotl32(x1, 13); x1 ^= x0;
  x0 += x1; x1 = rotl32(x1, 15); x1 ^= x0;
  x0 += x1; x1 = rotl32(x1, 26); x1 ^= x0;
  x0 += x1; x1 = rotl32(x1,  6); x1 ^= x0;
  x0 += ks0; x1 += ks1 + 3u;
  x0 += x1; x1 = rotl32(x1, 17); x1 ^= x0;
  x0 += x1; x1 = rotl32(x1, 29); x1 ^= x0;
  x0 += x1; x1 = rotl32(x1, 16); x1 ^= x0;
  x0 += x1; x1 = rotl32(x1, 24); x1 ^= x0;
  x0 += ks1; x1 += ks2 + 4u;
  x0 += x1; x1 = rotl32(x1, 13); x1 ^= x0;
  x0 += x1; x1 = rotl32(x1, 15); x1 ^= x0;
  x0 += x1; x1 = rotl32(x1, 26); x1 ^= x0;
  x0 += x1; x1 = rotl32(x1,  6); x1 ^= x0;
  x0 += ks2; x1 += ks0 + 5u;
  return {x0, x1};
}

// ---- compile-time key derivation (jax.random.key(42) == (0,42)) -----------
constexpr TFPair KM = tf2x32(0u, 42u, 0u, 0u);   // kmask = split(key)[0]
constexpr TFPair KP = tf2x32(0u, 42u, 0u, 1u);   // kperm = split(key)[1]
constexpr TFPair C2 = tf2x32(KM.a, KM.b, 0u, 1u);   // k2 of split(kmask)
constexpr uint32_t KLO0 = C2.a, KLO1 = C2.b;
constexpr TFPair SB = tf2x32(KP.a, KP.b, 0u, 1u);   // subkey of split(kperm)
constexpr uint32_t KSUB0 = SB.a, KSUB1 = SB.b;

// ---- compile-time permutation: inv_perm[m] = stable rank of sortkey[m] ----
struct Keys { uint32_t v[NC]; };
constexpr Keys make_keys() {
  Keys k{};
  for (int i = 0; i < NC; ++i) {
    TFPair r = tf2x32(KSUB0, KSUB1, 0u, (uint32_t)i);
    k.v[i] = r.a ^ r.b;          // 32-bit random_bits, partitionable: hi^lo
  }
  return k;
}
constexpr Keys KEYS = make_keys();

#define PART_SZ 33
struct Part { int v[PART_SZ]; };
constexpr Part make_part(int lo) {
  Part p{};
  for (int m = lo; m < lo + PART_SZ && m < NC; ++m) {
    uint32_t km = KEYS.v[m];
    int rank = 0;
    for (int j = 0; j < NC; ++j) {
      uint32_t kj = KEYS.v[j];
      if (kj < km || (kj == km && j < m)) ++rank;
    }
    p.v[m - lo] = rank;
  }
  return p;
}
// 16 separate constexpr variables: each gets its own constexpr step budget.
constexpr Part PT0  = make_part(0),   PT1  = make_part(33),
               PT2  = make_part(66),  PT3  = make_part(99),
               PT4  = make_part(132), PT5  = make_part(165),
               PT6  = make_part(198), PT7  = make_part(231),
               PT8  = make_part(264), PT9  = make_part(297),
               PT10 = make_part(330), PT11 = make_part(363),
               PT12 = make_part(396), PT13 = make_part(429),
               PT14 = make_part(462), PT15 = make_part(495);

struct IPerm { int v[NC]; };
constexpr IPerm merge_parts() {
  IPerm r{};
  const Part* ps[16] = {&PT0, &PT1, &PT2,  &PT3,  &PT4,  &PT5,  &PT6,  &PT7,
                        &PT8, &PT9, &PT10, &PT11, &PT12, &PT13, &PT14, &PT15};
  for (int c = 0; c < 16; ++c)
    for (int i = 0; i < PART_SZ; ++i) {
      int m = c * PART_SZ + i;
      if (m < NC) r.v[m] = ps[c]->v[i];
    }
  return r;
}
constexpr IPerm IPERM = merge_parts();
__device__ __constant__ IPerm d_iperm = IPERM;

// ---- dist kernel: grid (128 t-blocks, 64 j-groups), block 256 = 16t x 16tp -
__global__ __launch_bounds__(256) void dist_kernel(
    const int* __restrict__ locations, const int* __restrict__ pos_idx,
    const float* __restrict__ norm, float* __restrict__ out) {
  const int jg = blockIdx.y;                             // 0..63, scalar
  const int t  = ((int)blockIdx.x << 4) | ((int)threadIdx.x >> 4);
  const int tp = (int)threadIdx.x & 15;

  const int   ori  = locations[pos_idx[t] * TP_ + tp];
  const float nm   = norm[t];
  const float nm16 = nm * 0.0625f;
  float* outb = out + ((size_t)t * (NC * TP_) + tp);

  // the 'ori' channel: dist(ori,ori) = (1 - 1/16)*norm, written once (jg==0)
  if (jg == 0) outb[d_iperm.v[256] * TP_] = 0.9375f * nm;

#pragma unroll
  for (int jj = 0; jj < 4; ++jj) {
    const int j = (jg << 2) | jj;                        // 0..255, scalar
    const int h = j >> 4, k = j & (K_ - 1);              // scalar
    // flat index into (H, T, K, TP) mask tensor
    const uint32_t idx = (uint32_t)(((h * T_ + t) * K_ + k) * TP_ + tp);
    const TFPair r = tf2x32(KLO0, KLO1, 0u, idx);        // 64b word (a<<32)|b
    // flip bit h, xor the (2^h-1)-masked random bits; one scalar-const fold
    const uint32_t fm = (1u << h) ^ (r.b & ((1u << h) - 1u));
    const int v = ori ^ (int)fm;

    // dist(v, ori) = sign(v)*sign(ori) * (1 - bitlen(|v|^|ori|+1)/16) * norm
    const uint32_t sgbit = ((uint32_t)(v ^ ori)) & 0x80000000u;
    const uint32_t av = (uint32_t)(v   < 0 ? -v   : v);
    const uint32_t ao = (uint32_t)(ori < 0 ? -ori : ori);
    const uint32_t x  = (av ^ ao) + 1u;                  // <= 2^16, exact f32
    const int e = 32 - __clz((int)x);                    // bit length
    const float f  = nm - (float)e * nm16;               // (1 - e/16)*nm
    const float d1 = __uint_as_float(__float_as_uint(f) ^ sgbit);
    // dist(-v, ori): |v| unchanged, sign flips unless v==0
    const float d2 = (v == 0) ? d1
                   : __uint_as_float(__float_as_uint(d1) ^ 0x80000000u);

    outb[d_iperm.v[j]       * TP_] = d1;
    outb[d_iperm.v[j + 257] * TP_] = d2;
  }
}

extern "C" void kernel_launch(void* const* d_in, const int* in_sizes, int n_in,
                              void* d_out, int out_size, void* d_ws, size_t ws_size,
                              hipStream_t stream) {
  const int*   locations = (const int*)d_in[0];
  const int*   pos_idx   = (const int*)d_in[1];
  const float* norm      = (const float*)d_in[2];
  float* out = (float*)d_out;

  hipLaunchKernelGGL(dist_kernel, dim3(128, 64), dim3(256), 0, stream,
                     locations, pos_idx, norm, out);
}